// Round 1
// baseline (400.880 us; speedup 1.0000x reference)
//
#include <hip/hip_runtime.h>

#define OUT_F 11008
#define IN_F  4096
#define NBATCH 8
#define R 4                      // output rows per wave
#define BLOCK 64                 // one wave per block
#define NGR 32                   // groups per row = IN_F/128
#define KITERS (IN_F / (4 * BLOCK))   // 16 logical iters: lane covers 4 cols/iter
#define JITERS (KITERS / 2)           // 8 double-iters, depth-2 idx prefetch

// ext_vector aliases: __builtin_nontemporal_load needs scalar/vector types
typedef int   vint4   __attribute__((ext_vector_type(4)));
typedef float vfloat4 __attribute__((ext_vector_type(4)));

// R13: depth-2 idx prefetch (8 KB/wave in flight vs 4 KB).
// Theory: kernel is MLP-bound, not VALU-bound and not dirty-L3-bound
// (nt-loads were neutral -> Theory C refuted; fill's WRITE_SIZE drains to
// HBM during the fill itself). Grid = 2752 -> 10.75 waves/CU, 1-deep
// prefetch -> ~43 KB outstanding idx per CU -> implied iter period ~12k cyc
// waiting on vmcnt. Double the in-flight window, keep everything else.
// xv loads split 2x4 batches to hold peak VGPR ~150 (<=170 keeps 12 w/CU).

#define PROCESS(cvar, idxbuf)                                              \
    {                                                                      \
        const int c_ = (cvar);                                             \
        const int gcol_ = (c_ >> 7) * 16;                                  \
        float w_[R][4];                                                    \
        _Pragma("unroll")                                                  \
        for (int r = 0; r < R; ++r) {                                      \
            const float* lr_ = lutS + r * (NGR * 16) + gcol_;              \
            w_[r][0] = lr_[idxbuf[r].x];                                   \
            w_[r][1] = lr_[idxbuf[r].y];                                   \
            w_[r][2] = lr_[idxbuf[r].z];                                   \
            w_[r][3] = lr_[idxbuf[r].w];                                   \
        }                                                                  \
        _Pragma("unroll")                                                  \
        for (int g = 0; g < 2; ++g) {                                      \
            float4 xv_[4];                                                 \
            _Pragma("unroll")                                              \
            for (int mm = 0; mm < 4; ++mm)                                 \
                xv_[mm] = *reinterpret_cast<const float4*>(                \
                    x + (4 * g + mm) * IN_F + c_);                         \
            _Pragma("unroll")                                              \
            for (int mm = 0; mm < 4; ++mm) {                               \
                const int m_ = 4 * g + mm;                                 \
                _Pragma("unroll")                                          \
                for (int r = 0; r < R; ++r) {                              \
                    float a_ = acc[r][m_];                                 \
                    a_ = fmaf(w_[r][0], xv_[mm].x, a_);                    \
                    a_ = fmaf(w_[r][1], xv_[mm].y, a_);                    \
                    a_ = fmaf(w_[r][2], xv_[mm].z, a_);                    \
                    a_ = fmaf(w_[r][3], xv_[mm].w, a_);                    \
                    acc[r][m_] = a_;                                       \
                }                                                          \
            }                                                              \
        }                                                                  \
    }

__global__ __launch_bounds__(BLOCK, 3) void pal_linear_kernel(
    const float* __restrict__ x,        // [8, 4096]
    const int*   __restrict__ widx,     // [11008*4096] in [0,16)
    const float* __restrict__ lut,      // [352256, 16] f32 on device
    const float* __restrict__ bias,     // [11008]
    float* __restrict__ out)            // [8, 11008]
{
    __shared__ float lutS[R * NGR * 16];   // 8 KB wave-private slice

    const int tid = threadIdx.x;           // lane 0..63
    const int o0  = blockIdx.x * R;

    // stage the tile's LUT slice (nt: read-once stream, don't pollute/evict)
    {
        const vfloat4* src = reinterpret_cast<const vfloat4*>(lut + (size_t)o0 * NGR * 16);
        float4* dst = reinterpret_cast<float4*>(lutS);
#pragma unroll
        for (int i = 0; i < (R * NGR * 16 / 4) / BLOCK; ++i) {   // 8 iters
            const vfloat4 v = __builtin_nontemporal_load(src + tid + i * BLOCK);
            dst[tid + i * BLOCK] = make_float4(v.x, v.y, v.z, v.w);
        }
    }
    __syncthreads();

    float acc[R][NBATCH];
#pragma unroll
    for (int r = 0; r < R; ++r)
#pragma unroll
        for (int m = 0; m < NBATCH; ++m) acc[r][m] = 0.0f;

    // depth-2 prefetch ring: cur pair (two logical iters) + nxt pair
    vint4 curA[R], curB[R], nxtA[R], nxtB[R];
#pragma unroll
    for (int r = 0; r < R; ++r) {
        const int* p = widx + (size_t)(o0 + r) * IN_F + 4 * tid;
        curA[r] = __builtin_nontemporal_load(reinterpret_cast<const vint4*>(p));
        curB[r] = __builtin_nontemporal_load(reinterpret_cast<const vint4*>(p + 256));
    }

#pragma unroll 1
    for (int j = 0; j < JITERS; ++j) {
        const int cA = 4 * tid + 512 * j;   // logical iter 2j
        const int cB = cA + 256;            // logical iter 2j+1

        // prefetch next double-iter (8 x vint4 = 8 KB/wave in flight)
        if (j + 1 < JITERS) {
#pragma unroll
            for (int r = 0; r < R; ++r) {
                const int* p = widx + (size_t)(o0 + r) * IN_F + cA;
                nxtA[r] = __builtin_nontemporal_load(
                    reinterpret_cast<const vint4*>(p + 512));
                nxtB[r] = __builtin_nontemporal_load(
                    reinterpret_cast<const vint4*>(p + 768));
            }
        }

        PROCESS(cA, curA);
        PROCESS(cB, curB);

        if (j + 1 < JITERS) {
#pragma unroll
            for (int r = 0; r < R; ++r) {
                curA[r] = nxtA[r];
                curB[r] = nxtB[r];
            }
        }
    }

    // full-wave butterfly reduce
#pragma unroll
    for (int r = 0; r < R; ++r)
#pragma unroll
        for (int m = 0; m < NBATCH; ++m) {
            float v = acc[r][m];
#pragma unroll
            for (int off = 32; off >= 1; off >>= 1)
                v += __shfl_xor(v, off, 64);
            acc[r][m] = v;
        }

    // static select (R5 lesson: no runtime indexing of register arrays)
    float v = 0.0f;
#pragma unroll
    for (int r = 0; r < R; ++r)
#pragma unroll
        for (int m = 0; m < NBATCH; ++m)
            if (tid == r * NBATCH + m) v = acc[r][m];

    if (tid < R * NBATCH) {
        const int r = tid >> 3;
        const int m = tid & 7;
        out[(size_t)m * OUT_F + (o0 + r)] = v + bias[o0 + r];
    }
}

extern "C" void kernel_launch(void* const* d_in, const int* in_sizes, int n_in,
                              void* d_out, int out_size, void* d_ws, size_t ws_size,
                              hipStream_t stream) {
    const float* x    = (const float*)d_in[0];
    const int*   widx = (const int*)d_in[1];
    const float* lut  = (const float*)d_in[2];
    const float* bias = (const float*)d_in[3];
    float* out = (float*)d_out;

    pal_linear_kernel<<<OUT_F / R, BLOCK, 0, stream>>>(x, widx, lut, bias, out);
}

// Round 2
// 279.128 us; speedup vs baseline: 1.4362x; 1.4362x over previous
//
#include <hip/hip_runtime.h>

#define OUT_F 11008
#define IN_F  4096
#define NBATCH 8
#define R 4                      // output rows per wave
#define BLOCK 64                 // one wave per block
#define NGR 32                   // groups per row = IN_F/128
#define KITERS (IN_F / (4 * BLOCK))   // 16 iters: lane covers 4 cols per iter

#define NWORDS (OUT_F * IN_F / 4)     // 11,272,192 ushorts, 4 nibbles each
#define PACK_BLOCKS 2048
#define PACK_THREADS 256

// ext_vector aliases: __builtin_nontemporal_load needs scalar/vector types
typedef int   vint4   __attribute__((ext_vector_type(4)));
typedef float vfloat4 __attribute__((ext_vector_type(4)));

// R14: two-kernel split. The widx stream is 180MB of int32 carrying 4-bit
// payloads (32x inflation); every fused variant caps at 2.4-2.6 TB/s on it.
// Kernel A: pure-stream repack int32->nibble into d_ws (m13-shaped, should
// run ~6 TB/s). Kernel B: the known-good 79us structure, idx loads shrunk
// vint4->ushort (16B->2B per lane-row-iter), total idx traffic 22.5MB
// (partially L3-hot from A's writes). R13 lesson: 4x vint4xR prefetch
// buffers = 64 VGPR -> spill (WRITE_SIZE 309MB); ushort buffers cost 8.

__global__ __launch_bounds__(PACK_THREADS) void pack_kernel(
    const int* __restrict__ widx,            // [45,088,768] in [0,16)
    unsigned short* __restrict__ packed)     // [11,272,192] 4 nibbles each
{
    const int stride = gridDim.x * blockDim.x;
    const vint4* src = reinterpret_cast<const vint4*>(widx);
    for (int i = blockIdx.x * blockDim.x + threadIdx.x; i < NWORDS; i += stride) {
        const vint4 v = __builtin_nontemporal_load(src + i);   // 16B coalesced
        const unsigned short p = (unsigned short)(
            (v.x & 0xF) | ((v.y & 0xF) << 4) |
            ((v.z & 0xF) << 8) | ((v.w & 0xF) << 12));
        packed[i] = p;   // normal store: land in L2/L3 for kernel B
    }
}

__global__ __launch_bounds__(BLOCK) void pal_linear_kernel(
    const float* __restrict__ x,             // [8, 4096]
    const unsigned short* __restrict__ pidx, // [OUT_F * 1024] packed nibbles
    const float* __restrict__ lut,           // [352256, 16] f32 on device
    const float* __restrict__ bias,          // [11008]
    float* __restrict__ out)                 // [8, 11008]
{
    __shared__ float lutS[R * NGR * 16];     // 8 KB wave-private slice

    const int tid = threadIdx.x;             // lane 0..63
    const int o0  = blockIdx.x * R;

    // stage the tile's LUT slice (nt: read-once stream)
    {
        const vfloat4* src = reinterpret_cast<const vfloat4*>(lut + (size_t)o0 * NGR * 16);
        float4* dst = reinterpret_cast<float4*>(lutS);
#pragma unroll
        for (int i = 0; i < (R * NGR * 16 / 4) / BLOCK; ++i) {   // 8 iters
            const vfloat4 v = __builtin_nontemporal_load(src + tid + i * BLOCK);
            dst[tid + i * BLOCK] = make_float4(v.x, v.y, v.z, v.w);
        }
    }
    __syncthreads();

    float acc[R][NBATCH];
#pragma unroll
    for (int r = 0; r < R; ++r)
#pragma unroll
        for (int m = 0; m < NBATCH; ++m) acc[r][m] = 0.0f;

    // 1-deep prefetch, ushort per row = 8 VGPRs total for both buffers
    unsigned short icur[R], inxt[R];
#pragma unroll
    for (int r = 0; r < R; ++r)
        icur[r] = pidx[(size_t)(o0 + r) * (IN_F / 4) + tid];

#pragma unroll 1
    for (int k = 0; k < KITERS; ++k) {
        const int c = 4 * (tid + BLOCK * k);

        // 1) x loads (L2-hot — x IS reused across blocks)
        float4 xv[NBATCH];
#pragma unroll
        for (int m = 0; m < NBATCH; ++m)
            xv[m] = *reinterpret_cast<const float4*>(x + m * IN_F + c);

        // 2) idx prefetch (coalesced 128B/instr, mostly L3-hot)
        if (k + 1 < KITERS) {
#pragma unroll
            for (int r = 0; r < R; ++r)
                inxt[r] = pidx[(size_t)(o0 + r) * (IN_F / 4) + tid + BLOCK * (k + 1)];
        }

        // 3) LDS gathers with current indices (4 nibbles per row)
        const int gcol = (c >> 7) * 16;
        float w[R][4];
#pragma unroll
        for (int r = 0; r < R; ++r) {
            const float* lr = lutS + r * (NGR * 16) + gcol;
            const unsigned int u = icur[r];
            w[r][0] = lr[u & 0xF];
            w[r][1] = lr[(u >> 4) & 0xF];
            w[r][2] = lr[(u >> 8) & 0xF];
            w[r][3] = lr[(u >> 12) & 0xF];
        }

        // 4) FMAs (fully unrolled, all register-resident)
#pragma unroll
        for (int m = 0; m < NBATCH; ++m)
#pragma unroll
            for (int r = 0; r < R; ++r) {
                float a = acc[r][m];
                a = fmaf(w[r][0], xv[m].x, a);
                a = fmaf(w[r][1], xv[m].y, a);
                a = fmaf(w[r][2], xv[m].z, a);
                a = fmaf(w[r][3], xv[m].w, a);
                acc[r][m] = a;
            }

#pragma unroll
        for (int r = 0; r < R; ++r) icur[r] = inxt[r];
    }

    // full-wave butterfly reduce
#pragma unroll
    for (int r = 0; r < R; ++r)
#pragma unroll
        for (int m = 0; m < NBATCH; ++m) {
            float v = acc[r][m];
#pragma unroll
            for (int off = 32; off >= 1; off >>= 1)
                v += __shfl_xor(v, off, 64);
            acc[r][m] = v;
        }

    // static select (R5 lesson: no runtime indexing of register arrays)
    float v = 0.0f;
#pragma unroll
    for (int r = 0; r < R; ++r)
#pragma unroll
        for (int m = 0; m < NBATCH; ++m)
            if (tid == r * NBATCH + m) v = acc[r][m];

    if (tid < R * NBATCH) {
        const int r = tid >> 3;
        const int m = tid & 7;
        out[(size_t)m * OUT_F + (o0 + r)] = v + bias[o0 + r];
    }
}

extern "C" void kernel_launch(void* const* d_in, const int* in_sizes, int n_in,
                              void* d_out, int out_size, void* d_ws, size_t ws_size,
                              hipStream_t stream) {
    const float* x    = (const float*)d_in[0];
    const int*   widx = (const int*)d_in[1];
    const float* lut  = (const float*)d_in[2];
    const float* bias = (const float*)d_in[3];
    float* out = (float*)d_out;
    unsigned short* packed = (unsigned short*)d_ws;   // 22.5 MB of workspace

    pack_kernel<<<PACK_BLOCKS, PACK_THREADS, 0, stream>>>(widx, packed);
    pal_linear_kernel<<<OUT_F / R, BLOCK, 0, stream>>>(x, packed, lut, bias, out);
}